// Round 7
// baseline (1711.431 us; speedup 1.0000x reference)
//
#include <hip/hip_runtime.h>
#include <hip/hip_bf16.h>
#include <math.h>

typedef __bf16 bf16_t;
typedef __bf16 bf16x4 __attribute__((ext_vector_type(4)));
typedef __bf16 bf16x8 __attribute__((ext_vector_type(8)));
typedef float  f32x4  __attribute__((ext_vector_type(4)));

#define QKV_SCALE 0.17677669529663687f   // 32^-0.5
#define NWIN 4

// workspace offsets (bytes)
#define WS_QKVWT   0u          // [384][128] bf16 (Q rows pre-scaled)
#define WS_PROJWT  98304u      // [128][128] bf16
#define WS_QKVB    131072u     // [384] f32 (Q entries pre-scaled)
#define WS_MASKP   135168u     // [64][64][64] f32 mask, padded (kk>=49 -> -3e38)
#define WS_BIAST   1183744u    // [4][64][64] f32 mlp bias per head, padded 0

// ---------------------------------------------------------------- prep ----
__global__ __launch_bounds__(256) void prep_kernel(
    const float* __restrict__ mask,
    const float* __restrict__ qkv_w, const float* __restrict__ qkv_b,
    const float* __restrict__ mlp_w1, const float* __restrict__ mlp_b1,
    const float* __restrict__ mlp_w2, const float* __restrict__ mlp_b2,
    const float* __restrict__ proj_w,
    bf16_t* __restrict__ qkv_wT, bf16_t* __restrict__ proj_wT,
    float* __restrict__ qkv_bs, float* __restrict__ mask_pad,
    float* __restrict__ bias_t)
{
    const int blk = blockIdx.x;
    const int tid = threadIdx.x;
    if (blk < 1024) {
        // mask_pad[wi][q][kk]
        const int idx = blk * 256 + tid;           // 0..262143
        const int wi = idx >> 12, cell = idx & 4095;
        const int q = cell >> 6, kk = cell & 63;
        float val;
        if (q < 49 && kk < 49)      val = mask[wi * 2401 + q * 49 + kk];
        else if (kk >= 49)          val = -3.0e38f;
        else                        val = 0.0f;
        mask_pad[idx] = val;
    } else if (blk < 1040) {
        // bias_t[h][q][kk]
        const int cell = (blk - 1024) * 256 + tid; // 0..4095
        const int q = cell >> 6, kk = cell & 63;
        float b0 = 0.f, b1 = 0.f, b2 = 0.f, b3 = 0.f;
        if (q < 49 && kk < 49) {
            const float dy = (float)(q / 7 - kk / 7) * (1.0f / 6.0f);
            const float dx = (float)(q % 7 - kk % 7) * (1.0f / 6.0f);
            b0 = mlp_b2[0]; b1 = mlp_b2[1]; b2 = mlp_b2[2]; b3 = mlp_b2[3];
            for (int j = 0; j < 64; ++j) {
                const float pre = dy * mlp_w1[j] + dx * mlp_w1[64 + j] + mlp_b1[j];
                const float g = 0.5f * pre * (1.0f + erff(pre * 0.70710678118654752f));
                b0 += g * mlp_w2[j * 4 + 0];
                b1 += g * mlp_w2[j * 4 + 1];
                b2 += g * mlp_w2[j * 4 + 2];
                b3 += g * mlp_w2[j * 4 + 3];
            }
        }
        bias_t[0 * 4096 + cell] = b0;
        bias_t[1 * 4096 + cell] = b1;
        bias_t[2 * 4096 + cell] = b2;
        bias_t[3 * 4096 + cell] = b3;
    } else if (blk < 1232) {
        const int idx = (blk - 1040) * 256 + tid;  // 0..49151
        const int n = idx >> 7, k = idx & 127;
        float v = qkv_w[k * 384 + n];
        if (n < 128) v *= QKV_SCALE;
        qkv_wT[idx] = (bf16_t)v;
    } else if (blk < 1296) {
        const int idx = (blk - 1232) * 256 + tid;  // 0..16383
        const int n = idx >> 7, k = idx & 127;
        proj_wT[idx] = (bf16_t)proj_w[k * 128 + n];
    } else {
        if (tid < 384) {
            float v = qkv_b[tid];
            if (tid < 128) v *= QKV_SCALE;
            qkv_bs[tid] = v;
        }
    }
}

// ---------------------------------------------------------------- main ----
// Persistent blocks: 4096 blocks x 4 windows. LDS 32 KiB:
//   [0,16384)        : xb [64 tok][128] bf16 (swz) -> os overlay after PV
//   [16384 + w*4096) : per-wave vt [32 dim][64 tok] bf16 (swz), tokens stored
//                      in QUAD-PERMUTED order (see below) so the natural
//                      ds_read enumeration matches Pf's accumulator packing.
// swizzle byte ^= ((row&7)<<4) on write AND read.
__global__ __launch_bounds__(256, 4) void swin_main_kernel(
    const float* __restrict__ x,
    const bf16_t* __restrict__ qkv_wT,
    const bf16_t* __restrict__ proj_wT,
    const float* __restrict__ qkv_bs,
    const float* __restrict__ proj_b,
    const float* __restrict__ mask_pad,
    const float* __restrict__ bias_t,
    float* __restrict__ out)
{
    __shared__ __align__(16) unsigned char smem[32768];

    const int tid  = threadIdx.x;
    const int w    = tid >> 6;
    const int lane = tid & 63;
    const int c16  = lane & 15;
    const int q4   = lane >> 4;
    const int swz  = (c16 & 7) << 4;
    const int VB   = 16384 + w * 4096;
    const f32x4 zf = {0.f, 0.f, 0.f, 0.f};
    const float* bt = bias_t + (w << 12);

    // staging geometry: 4 chunks/thread, 32 B each
    const int srow = tid >> 4;                     // 0..15 (+16 per chunk)
    const int sk8  = (tid & 15) << 3;

    for (int i = 0; i < NWIN; ++i) {
        const int win = blockIdx.x * NWIN + i;

        // ---- stage x -> xb (bf16, swizzled); rows 49..63 zeroed ----
        __syncthreads();   // previous window's proj reads done
        {
            const float* xg = x + (size_t)win * 6272;
#pragma unroll
            for (int cc = 0; cc < 4; ++cc) {
                const int row = srow + 16 * cc;
                const int off = ((row << 8) + (sk8 << 1)) ^ ((row & 7) << 4);
                bf16x8 v;
                if (row < 49) {
                    const float4 a0 = *(const float4*)(xg + row * 128 + sk8);
                    const float4 a1 = *(const float4*)(xg + row * 128 + sk8 + 4);
                    v[0] = (bf16_t)a0.x; v[1] = (bf16_t)a0.y;
                    v[2] = (bf16_t)a0.z; v[3] = (bf16_t)a0.w;
                    v[4] = (bf16_t)a1.x; v[5] = (bf16_t)a1.y;
                    v[6] = (bf16_t)a1.z; v[7] = (bf16_t)a1.w;
                } else {
#pragma unroll
                    for (int j = 0; j < 8; ++j) v[j] = (bf16_t)0.0f;
                }
                *(bf16x8*)&smem[off] = v;
            }
        }
        __syncthreads();

        // ================= GEMM1 pass A: Q0,Q1,K0 =================
        const int colA[3] = {32 * w, 32 * w + 16, 128 + 32 * w};
        f32x4 acc[3][4];
#pragma unroll
        for (int m = 0; m < 3; ++m)
#pragma unroll
            for (int nt = 0; nt < 4; ++nt) acc[m][nt] = zf;
#pragma unroll
        for (int ks = 0; ks < 4; ++ks) {
            bf16x8 xf[4];
#pragma unroll
            for (int nt = 0; nt < 4; ++nt) {
                const int row = c16 + 16 * nt;
                xf[nt] = *(const bf16x8*)&smem[((row << 8) + ((ks * 32 + q4 * 8) << 1)) ^ swz];
            }
#pragma unroll
            for (int m = 0; m < 3; ++m) {
                const bf16x8 wf = *(const bf16x8*)(qkv_wT + (colA[m] + c16) * 128 + ks * 32 + q4 * 8);
#pragma unroll
                for (int nt = 0; nt < 4; ++nt)
                    acc[m][nt] = __builtin_amdgcn_mfma_f32_16x16x32_bf16(wf, xf[nt], acc[m][nt], 0, 0, 0);
            }
        }
        bf16x8 Qf[4], Kf[4];
        {
            const float4 b0 = *(const float4*)(qkv_bs + colA[0] + 4 * q4);
            const float4 b1 = *(const float4*)(qkv_bs + colA[1] + 4 * q4);
            const float4 b2 = *(const float4*)(qkv_bs + colA[2] + 4 * q4);
#pragma unroll
            for (int nt = 0; nt < 4; ++nt) {
                Qf[nt][0] = (bf16_t)(acc[0][nt][0] + b0.x); Qf[nt][1] = (bf16_t)(acc[0][nt][1] + b0.y);
                Qf[nt][2] = (bf16_t)(acc[0][nt][2] + b0.z); Qf[nt][3] = (bf16_t)(acc[0][nt][3] + b0.w);
                Qf[nt][4] = (bf16_t)(acc[1][nt][0] + b1.x); Qf[nt][5] = (bf16_t)(acc[1][nt][1] + b1.y);
                Qf[nt][6] = (bf16_t)(acc[1][nt][2] + b1.z); Qf[nt][7] = (bf16_t)(acc[1][nt][3] + b1.w);
                Kf[nt][0] = (bf16_t)(acc[2][nt][0] + b2.x); Kf[nt][1] = (bf16_t)(acc[2][nt][1] + b2.y);
                Kf[nt][2] = (bf16_t)(acc[2][nt][2] + b2.z); Kf[nt][3] = (bf16_t)(acc[2][nt][3] + b2.w);
            }
        }

        // ================= GEMM1 pass B: K1,V0,V1 =================
        const int colB = 128 + 32 * w + 16;
        f32x4 accK[4];     // K1
        f32x4 accV[4][2];  // [token tile][vcol tile]
#pragma unroll
        for (int nt = 0; nt < 4; ++nt) {
            accK[nt] = zf; accV[nt][0] = zf; accV[nt][1] = zf;
        }
#pragma unroll
        for (int ks = 0; ks < 4; ++ks) {
            bf16x8 xf[4];
#pragma unroll
            for (int nt = 0; nt < 4; ++nt) {
                const int row = c16 + 16 * nt;
                xf[nt] = *(const bf16x8*)&smem[((row << 8) + ((ks * 32 + q4 * 8) << 1)) ^ swz];
            }
            {
                const bf16x8 wf = *(const bf16x8*)(qkv_wT + (colB + c16) * 128 + ks * 32 + q4 * 8);
#pragma unroll
                for (int nt = 0; nt < 4; ++nt)
                    accK[nt] = __builtin_amdgcn_mfma_f32_16x16x32_bf16(wf, xf[nt], accK[nt], 0, 0, 0);
            }
#pragma unroll
            for (int ntv = 0; ntv < 2; ++ntv) {
                const bf16x8 vf = *(const bf16x8*)(qkv_wT + (256 + 32 * w + 16 * ntv + c16) * 128 + ks * 32 + q4 * 8);
#pragma unroll
                for (int mt = 0; mt < 4; ++mt)
                    accV[mt][ntv] = __builtin_amdgcn_mfma_f32_16x16x32_bf16(xf[mt], vf, accV[mt][ntv], 0, 0, 0);
            }
        }
        {
            const float4 b3 = *(const float4*)(qkv_bs + colB + 4 * q4);
#pragma unroll
            for (int nt = 0; nt < 4; ++nt) {
                Kf[nt][4] = (bf16_t)(accK[nt][0] + b3.x); Kf[nt][5] = (bf16_t)(accK[nt][1] + b3.y);
                Kf[nt][6] = (bf16_t)(accK[nt][2] + b3.z); Kf[nt][7] = (bf16_t)(accK[nt][3] + b3.w);
            }
        }
        // V -> vt LDS, QUAD-PERMUTED token order:
        //   writer quad (mt,q4,r) holds token 16*mt+4*q4+r; place it at linear
        //   slot 32*(mt>>1) + 8*q4 + 4*(mt&1) + r so the natural-order PV read
        //   (elem j at slot 32*ksv+8*q4+j) yields token 32*ksv+16*(j>>2)+4*q4+(j&3),
        //   exactly matching Pf's accumulator-quad packing. (R6 bug: A/B used
        //   different contraction enumerations.)
#pragma unroll
        for (int ntv = 0; ntv < 2; ++ntv) {
            const float qv = qkv_bs[256 + 32 * w + 16 * ntv + c16];
            const int dim = c16 + 16 * ntv;
#pragma unroll
            for (int mt = 0; mt < 4; ++mt) {
                const int tok0 = 32 * (mt >> 1) + 8 * q4 + 4 * (mt & 1);
                bf16x4 pk;
                pk[0] = (bf16_t)(accV[mt][ntv][0] + qv);
                pk[1] = (bf16_t)(accV[mt][ntv][1] + qv);
                pk[2] = (bf16_t)(accV[mt][ntv][2] + qv);
                pk[3] = (bf16_t)(accV[mt][ntv][3] + qv);
                *(bf16x4*)&smem[(VB + dim * 128 + tok0 * 2) ^ ((dim & 7) << 4)] = pk;
            }
        }

        // ================= S^T = K · Q^T =================
        f32x4 st[4][4];
#pragma unroll
        for (int mtk = 0; mtk < 4; ++mtk)
#pragma unroll
            for (int ntq = 0; ntq < 4; ++ntq)
                st[mtk][ntq] = __builtin_amdgcn_mfma_f32_16x16x32_bf16(Kf[mtk], Qf[ntq], zf, 0, 0, 0);

        // ========== softmax + P pack (pre-normalized) ==========
        const float* mp = mask_pad + ((size_t)(win & 63) << 12);
        bf16x8 Pf[4][2];
#pragma unroll
        for (int ntq = 0; ntq < 4; ++ntq) {
            const int q = c16 + 16 * ntq;
            float mx = -3.0e38f;
#pragma unroll
            for (int mt = 0; mt < 4; ++mt) {
                const float4 mv = *(const float4*)(mp + q * 64 + 16 * mt + 4 * q4);
                const float4 bv = *(const float4*)(bt + q * 64 + 16 * mt + 4 * q4);
                st[mt][ntq][0] += mv.x + bv.x; st[mt][ntq][1] += mv.y + bv.y;
                st[mt][ntq][2] += mv.z + bv.z; st[mt][ntq][3] += mv.w + bv.w;
#pragma unroll
                for (int r = 0; r < 4; ++r) mx = fmaxf(mx, st[mt][ntq][r]);
            }
            mx = fmaxf(mx, __shfl_xor(mx, 16));
            mx = fmaxf(mx, __shfl_xor(mx, 32));
            float sm = 0.0f;
#pragma unroll
            for (int mt = 0; mt < 4; ++mt)
#pragma unroll
                for (int r = 0; r < 4; ++r) {
                    const float p = __expf(st[mt][ntq][r] - mx);
                    st[mt][ntq][r] = p;
                    sm += p;
                }
            sm += __shfl_xor(sm, 16);
            sm += __shfl_xor(sm, 32);
            const float rp = 1.0f / sm;
#pragma unroll
            for (int ksv = 0; ksv < 2; ++ksv) {
#pragma unroll
                for (int r = 0; r < 4; ++r) {
                    Pf[ntq][ksv][r]     = (bf16_t)(st[2 * ksv][ntq][r] * rp);
                    Pf[ntq][ksv][4 + r] = (bf16_t)(st[2 * ksv + 1][ntq][r] * rp);
                }
            }
        }

        // ================= O^T = V · P^T (vt from LDS) =================
        f32x4 ot[2][4];
#pragma unroll
        for (int mtd = 0; mtd < 2; ++mtd)
#pragma unroll
            for (int ntq = 0; ntq < 4; ++ntq) ot[mtd][ntq] = zf;
#pragma unroll
        for (int ksv = 0; ksv < 2; ++ksv) {
            bf16x8 av[2];
#pragma unroll
            for (int mtd = 0; mtd < 2; ++mtd)
                av[mtd] = *(const bf16x8*)&smem[(VB + (c16 + 16 * mtd) * 128 + 64 * ksv + 16 * q4) ^ swz];
#pragma unroll
            for (int mtd = 0; mtd < 2; ++mtd)
#pragma unroll
                for (int ntq = 0; ntq < 4; ++ntq)
                    ot[mtd][ntq] = __builtin_amdgcn_mfma_f32_16x16x32_bf16(av[mtd], Pf[ntq][ksv], ot[mtd][ntq], 0, 0, 0);
        }

        __syncthreads();   // all waves done reading xb -> overlay os

        // ---- O^T -> os (overlay xb) ----
#pragma unroll
        for (int mtd = 0; mtd < 2; ++mtd)
#pragma unroll
            for (int ntq = 0; ntq < 4; ++ntq) {
                const int tok = c16 + 16 * ntq;
                bf16x4 pk;
#pragma unroll
                for (int r = 0; r < 4; ++r) pk[r] = (bf16_t)ot[mtd][ntq][r];
                *(bf16x4*)&smem[(tok * 256 + (32 * w + 16 * mtd + 4 * q4) * 2) ^ swz] = pk;
            }
        __syncthreads();

        // ================= proj (interleaved ocols) =================
        f32x4 pj[2][4];
#pragma unroll
        for (int mt = 0; mt < 2; ++mt)
#pragma unroll
            for (int ntq = 0; ntq < 4; ++ntq) pj[mt][ntq] = zf;

        const int oc_il = 32 * w + 8 * (c16 >> 2) + (c16 & 3);
#pragma unroll
        for (int ks = 0; ks < 4; ++ks) {
            const bf16x8 aw0 = *(const bf16x8*)(proj_wT + (oc_il + 0) * 128 + ks * 32 + q4 * 8);
            const bf16x8 aw1 = *(const bf16x8*)(proj_wT + (oc_il + 4) * 128 + ks * 32 + q4 * 8);
#pragma unroll
            for (int ntq = 0; ntq < 4; ++ntq) {
                const bf16x8 bo = *(const bf16x8*)&smem[(((c16 + 16 * ntq) * 256) + ks * 64 + q4 * 16) ^ swz];
                pj[0][ntq] = __builtin_amdgcn_mfma_f32_16x16x32_bf16(aw0, bo, pj[0][ntq], 0, 0, 0);
                pj[1][ntq] = __builtin_amdgcn_mfma_f32_16x16x32_bf16(aw1, bo, pj[1][ntq], 0, 0, 0);
            }
        }

        // ---- store: 32 contiguous bytes per lane per q-tile ----
        float* og = out + (size_t)win * 6272;
        const int oc0 = 32 * w + 8 * q4;
        const float4 pb0 = *(const float4*)(proj_b + oc0);
        const float4 pb1 = *(const float4*)(proj_b + oc0 + 4);
#pragma unroll
        for (int ntq = 0; ntq < 4; ++ntq) {
            const int tok = c16 + 16 * ntq;
            if (tok < 49) {
                float4 v0, v1;
                v0.x = pj[0][ntq][0] + pb0.x; v0.y = pj[0][ntq][1] + pb0.y;
                v0.z = pj[0][ntq][2] + pb0.z; v0.w = pj[0][ntq][3] + pb0.w;
                v1.x = pj[1][ntq][0] + pb1.x; v1.y = pj[1][ntq][1] + pb1.y;
                v1.z = pj[1][ntq][2] + pb1.z; v1.w = pj[1][ntq][3] + pb1.w;
                *(float4*)(og + tok * 128 + oc0)     = v0;
                *(float4*)(og + tok * 128 + oc0 + 4) = v1;
            }
        }
    }
}

// -------------------------------------------------------------- launch ----
extern "C" void kernel_launch(void* const* d_in, const int* in_sizes, int n_in,
                              void* d_out, int out_size, void* d_ws, size_t ws_size,
                              hipStream_t stream) {
    const float* x      = (const float*)d_in[0];
    const float* mask   = (const float*)d_in[1];
    const float* qkv_w  = (const float*)d_in[2];
    const float* qkv_b  = (const float*)d_in[3];
    const float* mlp_w1 = (const float*)d_in[4];
    const float* mlp_b1 = (const float*)d_in[5];
    const float* mlp_w2 = (const float*)d_in[6];
    const float* mlp_b2 = (const float*)d_in[7];
    const float* proj_w = (const float*)d_in[8];
    const float* proj_b = (const float*)d_in[9];
    float* out = (float*)d_out;

    unsigned char* ws = (unsigned char*)d_ws;
    bf16_t* qkv_wT   = (bf16_t*)(ws + WS_QKVWT);
    bf16_t* proj_wT  = (bf16_t*)(ws + WS_PROJWT);
    float*  qkv_bs   = (float*)(ws + WS_QKVB);
    float*  mask_pad = (float*)(ws + WS_MASKP);
    float*  bias_t   = (float*)(ws + WS_BIAST);

    hipLaunchKernelGGL(prep_kernel, dim3(1297), dim3(256), 0, stream,
                       mask, qkv_w, qkv_b, mlp_w1, mlp_b1, mlp_w2, mlp_b2, proj_w,
                       qkv_wT, proj_wT, qkv_bs, mask_pad, bias_t);
    hipLaunchKernelGGL(swin_main_kernel, dim3(16384 / NWIN), dim3(256), 0, stream,
                       x, qkv_wT, proj_wT, qkv_bs, proj_b, mask_pad, bias_t, out);
}

// Round 9
// 1237.582 us; speedup vs baseline: 1.3829x; 1.3829x over previous
//
#include <hip/hip_runtime.h>
#include <hip/hip_bf16.h>
#include <math.h>

typedef __bf16 bf16_t;
typedef __bf16 bf16x4 __attribute__((ext_vector_type(4)));
typedef __bf16 bf16x8 __attribute__((ext_vector_type(8)));
typedef float  f32x4  __attribute__((ext_vector_type(4)));

#define QKV_SCALE 0.17677669529663687f   // 32^-0.5

// workspace offsets (bytes)
#define WS_QKVWT   0u          // [384][128] bf16 (Q rows pre-scaled)
#define WS_PROJWT  98304u      // [128][128] bf16
#define WS_QKVB    131072u     // [384] f32 (Q entries pre-scaled)
#define WS_MASKP   135168u     // [64][64][64] f32 mask, padded (kk>=49 -> -3e38)
#define WS_BIAST   1183744u    // [4][64][64] f32 mlp bias per head, padded 0

// ---------------------------------------------------------------- prep ----
__global__ __launch_bounds__(256) void prep_kernel(
    const float* __restrict__ mask,
    const float* __restrict__ qkv_w, const float* __restrict__ qkv_b,
    const float* __restrict__ mlp_w1, const float* __restrict__ mlp_b1,
    const float* __restrict__ mlp_w2, const float* __restrict__ mlp_b2,
    const float* __restrict__ proj_w,
    bf16_t* __restrict__ qkv_wT, bf16_t* __restrict__ proj_wT,
    float* __restrict__ qkv_bs, float* __restrict__ mask_pad,
    float* __restrict__ bias_t)
{
    const int blk = blockIdx.x;
    const int tid = threadIdx.x;
    if (blk < 1024) {
        const int idx = blk * 256 + tid;           // mask_pad[wi][q][kk]
        const int wi = idx >> 12, cell = idx & 4095;
        const int q = cell >> 6, kk = cell & 63;
        float val;
        if (q < 49 && kk < 49)      val = mask[wi * 2401 + q * 49 + kk];
        else if (kk >= 49)          val = -3.0e38f;
        else                        val = 0.0f;
        mask_pad[idx] = val;
    } else if (blk < 1040) {
        const int cell = (blk - 1024) * 256 + tid; // bias_t[h][q][kk]
        const int q = cell >> 6, kk = cell & 63;
        float b0 = 0.f, b1 = 0.f, b2 = 0.f, b3 = 0.f;
        if (q < 49 && kk < 49) {
            const float dy = (float)(q / 7 - kk / 7) * (1.0f / 6.0f);
            const float dx = (float)(q % 7 - kk % 7) * (1.0f / 6.0f);
            b0 = mlp_b2[0]; b1 = mlp_b2[1]; b2 = mlp_b2[2]; b3 = mlp_b2[3];
            for (int j = 0; j < 64; ++j) {
                const float pre = dy * mlp_w1[j] + dx * mlp_w1[64 + j] + mlp_b1[j];
                const float g = 0.5f * pre * (1.0f + erff(pre * 0.70710678118654752f));
                b0 += g * mlp_w2[j * 4 + 0];
                b1 += g * mlp_w2[j * 4 + 1];
                b2 += g * mlp_w2[j * 4 + 2];
                b3 += g * mlp_w2[j * 4 + 3];
            }
        }
        bias_t[0 * 4096 + cell] = b0;
        bias_t[1 * 4096 + cell] = b1;
        bias_t[2 * 4096 + cell] = b2;
        bias_t[3 * 4096 + cell] = b3;
    } else if (blk < 1232) {
        const int idx = (blk - 1040) * 256 + tid;  // 0..49151
        const int n = idx >> 7, k = idx & 127;
        float v = qkv_w[k * 384 + n];
        if (n < 128) v *= QKV_SCALE;
        qkv_wT[idx] = (bf16_t)v;
    } else if (blk < 1296) {
        const int idx = (blk - 1232) * 256 + tid;  // 0..16383
        const int n = idx >> 7, k = idx & 127;
        proj_wT[idx] = (bf16_t)proj_w[k * 128 + n];
    } else {
        if (tid < 384) {
            float v = qkv_b[tid];
            if (tid < 128) v *= QKV_SCALE;
            qkv_bs[tid] = v;
        }
    }
}

// ---------------------------------------------------------------- main ----
// One window per 16-wave block. Wave (a,b): a = head / col-quad, b = token
// quarter. LDS 64 KiB:
//   [0,16384)     xb [64 tok][128 dim] bf16 (swz)  -> os overlay after PV
//   [16384,32768) Qb [64 tok][128 dim] bf16 (swz)
//   [32768,49152) Kb [64 tok][128 dim] bf16 (swz)
//   [49152,65536) Vt [128 dim][64 tok] bf16 (swz), tokens quad-permuted
//                 (slot = 32*(b>>1)+8*q4+4*(b&1)+r) matching Pf packing (R7).
// swizzle byte ^= ((row&7)<<4) on write AND read; rows ≡ c16 (mod 16).
__global__ __launch_bounds__(1024, 8) void swin_main_kernel(
    const float* __restrict__ x,
    const bf16_t* __restrict__ qkv_wT,
    const bf16_t* __restrict__ proj_wT,
    const float* __restrict__ qkv_bs,
    const float* __restrict__ proj_b,
    const float* __restrict__ mask_pad,
    const float* __restrict__ bias_t,
    float* __restrict__ out)
{
    __shared__ __align__(16) unsigned char smem[65536];
    const int QB = 16384, KBo = 32768, VT = 49152;

    const int win  = blockIdx.x;
    const int tid  = threadIdx.x;
    const int wv   = tid >> 6;          // 0..15
    const int a    = wv >> 2;           // head / col-quad
    const int b    = wv & 3;            // token quarter
    const int lane = tid & 63;
    const int c16  = lane & 15;
    const int q4   = lane >> 4;
    const int swz  = (c16 & 7) << 4;
    const f32x4 zf = {0.f, 0.f, 0.f, 0.f};

    // ---- stage x -> xb: 1 chunk (32 B) per thread ----
    {
        const int row = tid >> 4;
        const int k8  = (tid & 15) << 3;
        const int off = ((row << 8) + (k8 << 1)) ^ ((row & 7) << 4);
        const float* xg = x + (size_t)win * 6272;
        bf16x8 v;
        if (row < 49) {
            const float4 a0 = *(const float4*)(xg + row * 128 + k8);
            const float4 a1 = *(const float4*)(xg + row * 128 + k8 + 4);
            v[0] = (bf16_t)a0.x; v[1] = (bf16_t)a0.y;
            v[2] = (bf16_t)a0.z; v[3] = (bf16_t)a0.w;
            v[4] = (bf16_t)a1.x; v[5] = (bf16_t)a1.y;
            v[6] = (bf16_t)a1.z; v[7] = (bf16_t)a1.w;
        } else {
#pragma unroll
            for (int j = 0; j < 8; ++j) v[j] = (bf16_t)0.0f;
        }
        *(bf16x8*)&smem[off] = v;
    }
    __syncthreads();

    const int tokb = 16 * b + c16;           // token owned on the col-side
    const int trow = tokb << 8;              // row byte base (stride 256 B)

    // ================= GEMM1 QK (transposed): outcol tiles 4a..4a+3 =======
    f32x4 qk[4];
#pragma unroll
    for (int m = 0; m < 4; ++m) qk[m] = zf;
#pragma unroll
    for (int ks = 0; ks < 4; ++ks) {
        const bf16x8 xf = *(const bf16x8*)&smem[(trow + 64 * ks + 16 * q4) ^ swz];
#pragma unroll
        for (int m = 0; m < 4; ++m) {
            const int t = 4 * a + m;         // Q tiles 0-7, K tiles 8-15
            const bf16x8 wf = *(const bf16x8*)(qkv_wT + (16 * t + c16) * 128 + ks * 32 + q4 * 8);
            qk[m] = __builtin_amdgcn_mfma_f32_16x16x32_bf16(wf, xf, qk[m], 0, 0, 0);
        }
    }
    // epilogue: D(row=outcol 16t+4q4+r, col=token tokb) -> Qb/Kb b64 packed
#pragma unroll
    for (int m = 0; m < 4; ++m) {
        const int t = 4 * a + m;
        const float4 bi = *(const float4*)(qkv_bs + 16 * t + 4 * q4);
        bf16x4 pk;
        pk[0] = (bf16_t)(qk[m][0] + bi.x); pk[1] = (bf16_t)(qk[m][1] + bi.y);
        pk[2] = (bf16_t)(qk[m][2] + bi.z); pk[3] = (bf16_t)(qk[m][3] + bi.w);
        const int base = (t < 8) ? QB : KBo;
        const int dimb = (t < 8) ? (32 * t + 8 * q4) : (32 * (t - 8) + 8 * q4);
        *(bf16x4*)&smem[base + ((trow + dimb) ^ swz)] = pk;
    }

    // ================= GEMM1 V (natural): V col tiles 2a, 2a+1 ============
    f32x4 va[2];
    va[0] = zf; va[1] = zf;
#pragma unroll
    for (int ks = 0; ks < 4; ++ks) {
        const bf16x8 xf = *(const bf16x8*)&smem[(trow + 64 * ks + 16 * q4) ^ swz];
#pragma unroll
        for (int mv = 0; mv < 2; ++mv) {
            const int vc = 16 * (2 * a + mv) + c16;   // V outcol 0..127
            const bf16x8 vf = *(const bf16x8*)(qkv_wT + (256 + vc) * 128 + ks * 32 + q4 * 8);
            va[mv] = __builtin_amdgcn_mfma_f32_16x16x32_bf16(xf, vf, va[mv], 0, 0, 0);
        }
    }
    // epilogue: D(row=token 16b+4q4+r, col=vcol) -> Vt quad-permuted slots
    {
        const int slot2 = (32 * (b >> 1) + 8 * q4 + 4 * (b & 1)) << 1;
#pragma unroll
        for (int mv = 0; mv < 2; ++mv) {
            const int vc = 16 * (2 * a + mv) + c16;
            const float qv = qkv_bs[256 + vc];
            bf16x4 pk;
            pk[0] = (bf16_t)(va[mv][0] + qv); pk[1] = (bf16_t)(va[mv][1] + qv);
            pk[2] = (bf16_t)(va[mv][2] + qv); pk[3] = (bf16_t)(va[mv][3] + qv);
            *(bf16x4*)&smem[VT + (((vc << 7) + slot2) ^ swz)] = pk;
        }
    }
    __syncthreads();

    // ================= S^T = K · Q^T : 64 kk x 16 q (head a, q-quarter b) ==
    const bf16x8 Qf = *(const bf16x8*)&smem[QB + ((trow + 64 * a + 16 * q4) ^ swz)];
    f32x4 st[4];
#pragma unroll
    for (int mtk = 0; mtk < 4; ++mtk) {
        const bf16x8 Kf = *(const bf16x8*)&smem[KBo + ((((16 * mtk + c16) << 8) + 64 * a + 16 * q4) ^ swz)];
        st[mtk] = __builtin_amdgcn_mfma_f32_16x16x32_bf16(Kf, Qf, zf, 0, 0, 0);
    }

    // ========== softmax (lane col = q = tokb; kk = 16mtk+4q4+r) ===========
    const float* mp = mask_pad + ((size_t)(win & 63) << 12);
    const float* bt = bias_t + (a << 12);
    float mx = -3.0e38f;
#pragma unroll
    for (int mtk = 0; mtk < 4; ++mtk) {
        const float4 mv4 = *(const float4*)(mp + tokb * 64 + 16 * mtk + 4 * q4);
        const float4 bv4 = *(const float4*)(bt + tokb * 64 + 16 * mtk + 4 * q4);
        st[mtk][0] += mv4.x + bv4.x; st[mtk][1] += mv4.y + bv4.y;
        st[mtk][2] += mv4.z + bv4.z; st[mtk][3] += mv4.w + bv4.w;
#pragma unroll
        for (int r = 0; r < 4; ++r) mx = fmaxf(mx, st[mtk][r]);
    }
    mx = fmaxf(mx, __shfl_xor(mx, 16));
    mx = fmaxf(mx, __shfl_xor(mx, 32));
    float sm = 0.0f;
#pragma unroll
    for (int mtk = 0; mtk < 4; ++mtk)
#pragma unroll
        for (int r = 0; r < 4; ++r) {
            const float p = __expf(st[mtk][r] - mx);
            st[mtk][r] = p;
            sm += p;
        }
    sm += __shfl_xor(sm, 16);
    sm += __shfl_xor(sm, 32);
    const float rp = 1.0f / sm;
    bf16x8 Pf[2];
#pragma unroll
    for (int ksv = 0; ksv < 2; ++ksv)
#pragma unroll
        for (int r = 0; r < 4; ++r) {
            Pf[ksv][r]     = (bf16_t)(st[2 * ksv][r] * rp);
            Pf[ksv][4 + r] = (bf16_t)(st[2 * ksv + 1][r] * rp);
        }

    // ================= O^T = V · P^T (A from Vt, natural-enum read) =======
    f32x4 ot[2];
    ot[0] = zf; ot[1] = zf;
#pragma unroll
    for (int ksv = 0; ksv < 2; ++ksv)
#pragma unroll
        for (int mtd = 0; mtd < 2; ++mtd) {
            const bf16x8 av = *(const bf16x8*)&smem[VT + ((((32 * a + 16 * mtd + c16) << 7) + 64 * ksv + 16 * q4) ^ swz)];
            ot[mtd] = __builtin_amdgcn_mfma_f32_16x16x32_bf16(av, Pf[ksv], ot[mtd], 0, 0, 0);
        }

    // ---- O^T -> os (overlay xb; xb reads all completed pre-barrier-2) ----
#pragma unroll
    for (int mtd = 0; mtd < 2; ++mtd) {
        bf16x4 pk;
#pragma unroll
        for (int r = 0; r < 4; ++r) pk[r] = (bf16_t)ot[mtd][r];
        *(bf16x4*)&smem[(trow + ((32 * a + 16 * mtd + 4 * q4) << 1)) ^ swz] = pk;
    }
    __syncthreads();

    // ================= proj (interleaved ocols, R5-verified) ==============
    const int oc_il = 32 * a + 8 * (c16 >> 2) + (c16 & 3);
    f32x4 pj[2];
    pj[0] = zf; pj[1] = zf;
#pragma unroll
    for (int ks = 0; ks < 4; ++ks) {
        const bf16x8 bo  = *(const bf16x8*)&smem[(trow + 64 * ks + 16 * q4) ^ swz];
        const bf16x8 aw0 = *(const bf16x8*)(proj_wT + (oc_il + 0) * 128 + ks * 32 + q4 * 8);
        const bf16x8 aw1 = *(const bf16x8*)(proj_wT + (oc_il + 4) * 128 + ks * 32 + q4 * 8);
        pj[0] = __builtin_amdgcn_mfma_f32_16x16x32_bf16(aw0, bo, pj[0], 0, 0, 0);
        pj[1] = __builtin_amdgcn_mfma_f32_16x16x32_bf16(aw1, bo, pj[1], 0, 0, 0);
    }

    // ---- store: lane writes 32 contiguous bytes (2x float4) ----
    if (tokb < 49) {
        float* og = out + (size_t)win * 6272;
        const int oc0 = 32 * a + 8 * q4;
        const float4 pb0 = *(const float4*)(proj_b + oc0);
        const float4 pb1 = *(const float4*)(proj_b + oc0 + 4);
        float4 v0, v1;
        v0.x = pj[0][0] + pb0.x; v0.y = pj[0][1] + pb0.y;
        v0.z = pj[0][2] + pb0.z; v0.w = pj[0][3] + pb0.w;
        v1.x = pj[1][0] + pb1.x; v1.y = pj[1][1] + pb1.y;
        v1.z = pj[1][2] + pb1.z; v1.w = pj[1][3] + pb1.w;
        *(float4*)(og + tokb * 128 + oc0)     = v0;
        *(float4*)(og + tokb * 128 + oc0 + 4) = v1;
    }
}

// -------------------------------------------------------------- launch ----
extern "C" void kernel_launch(void* const* d_in, const int* in_sizes, int n_in,
                              void* d_out, int out_size, void* d_ws, size_t ws_size,
                              hipStream_t stream) {
    const float* x      = (const float*)d_in[0];
    const float* mask   = (const float*)d_in[1];
    const float* qkv_w  = (const float*)d_in[2];
    const float* qkv_b  = (const float*)d_in[3];
    const float* mlp_w1 = (const float*)d_in[4];
    const float* mlp_b1 = (const float*)d_in[5];
    const float* mlp_w2 = (const float*)d_in[6];
    const float* mlp_b2 = (const float*)d_in[7];
    const float* proj_w = (const float*)d_in[8];
    const float* proj_b = (const float*)d_in[9];
    float* out = (float*)d_out;

    unsigned char* ws = (unsigned char*)d_ws;
    bf16_t* qkv_wT   = (bf16_t*)(ws + WS_QKVWT);
    bf16_t* proj_wT  = (bf16_t*)(ws + WS_PROJWT);
    float*  qkv_bs   = (float*)(ws + WS_QKVB);
    float*  mask_pad = (float*)(ws + WS_MASKP);
    float*  bias_t   = (float*)(ws + WS_BIAST);

    hipLaunchKernelGGL(prep_kernel, dim3(1297), dim3(256), 0, stream,
                       mask, qkv_w, qkv_b, mlp_w1, mlp_b1, mlp_w2, mlp_b2, proj_w,
                       qkv_wT, proj_wT, qkv_bs, mask_pad, bias_t);
    hipLaunchKernelGGL(swin_main_kernel, dim3(16384), dim3(1024), 0, stream,
                       x, qkv_wT, proj_wT, qkv_bs, proj_b, mask_pad, bias_t, out);
}

// Round 10
// 795.818 us; speedup vs baseline: 2.1505x; 1.5551x over previous
//
#include <hip/hip_runtime.h>
#include <hip/hip_bf16.h>
#include <math.h>

typedef __bf16 bf16_t;
typedef __bf16 bf16x4 __attribute__((ext_vector_type(4)));
typedef __bf16 bf16x8 __attribute__((ext_vector_type(8)));
typedef float  f32x4  __attribute__((ext_vector_type(4)));

#define QKV_SCALE 0.17677669529663687f   // 32^-0.5

// workspace offsets (bytes)
#define WS_QKVWT   0u          // [384][128] bf16 (Q rows pre-scaled)
#define WS_PROJWT  98304u      // [128][128] bf16
#define WS_QKVB    131072u     // [384] f32 (Q entries pre-scaled)
#define WS_MASKP   135168u     // [64][64][64] f32 mask, padded (kk>=49 -> -3e38)
#define WS_BIAST   1183744u    // [4][64][64] f32 mlp bias per head, padded 0

// ---------------------------------------------------------------- prep ----
__global__ __launch_bounds__(256) void prep_kernel(
    const float* __restrict__ mask,
    const float* __restrict__ qkv_w, const float* __restrict__ qkv_b,
    const float* __restrict__ mlp_w1, const float* __restrict__ mlp_b1,
    const float* __restrict__ mlp_w2, const float* __restrict__ mlp_b2,
    const float* __restrict__ proj_w,
    bf16_t* __restrict__ qkv_wT, bf16_t* __restrict__ proj_wT,
    float* __restrict__ qkv_bs, float* __restrict__ mask_pad,
    float* __restrict__ bias_t)
{
    const int blk = blockIdx.x;
    const int tid = threadIdx.x;
    if (blk < 1024) {
        const int idx = blk * 256 + tid;           // mask_pad[wi][q][kk]
        const int wi = idx >> 12, cell = idx & 4095;
        const int q = cell >> 6, kk = cell & 63;
        float val;
        if (q < 49 && kk < 49)      val = mask[wi * 2401 + q * 49 + kk];
        else if (kk >= 49)          val = -3.0e38f;
        else                        val = 0.0f;
        mask_pad[idx] = val;
    } else if (blk < 1040) {
        const int cell = (blk - 1024) * 256 + tid; // bias_t[h][q][kk]
        const int q = cell >> 6, kk = cell & 63;
        float b0 = 0.f, b1 = 0.f, b2 = 0.f, b3 = 0.f;
        if (q < 49 && kk < 49) {
            const float dy = (float)(q / 7 - kk / 7) * (1.0f / 6.0f);
            const float dx = (float)(q % 7 - kk % 7) * (1.0f / 6.0f);
            b0 = mlp_b2[0]; b1 = mlp_b2[1]; b2 = mlp_b2[2]; b3 = mlp_b2[3];
            for (int j = 0; j < 64; ++j) {
                const float pre = dy * mlp_w1[j] + dx * mlp_w1[64 + j] + mlp_b1[j];
                const float g = 0.5f * pre * (1.0f + erff(pre * 0.70710678118654752f));
                b0 += g * mlp_w2[j * 4 + 0];
                b1 += g * mlp_w2[j * 4 + 1];
                b2 += g * mlp_w2[j * 4 + 2];
                b3 += g * mlp_w2[j * 4 + 3];
            }
        }
        bias_t[0 * 4096 + cell] = b0;
        bias_t[1 * 4096 + cell] = b1;
        bias_t[2 * 4096 + cell] = b2;
        bias_t[3 * 4096 + cell] = b3;
    } else if (blk < 1232) {
        const int idx = (blk - 1040) * 256 + tid;  // 0..49151
        const int n = idx >> 7, k = idx & 127;
        float v = qkv_w[k * 384 + n];
        if (n < 128) v *= QKV_SCALE;
        qkv_wT[idx] = (bf16_t)v;
    } else if (blk < 1296) {
        const int idx = (blk - 1232) * 256 + tid;  // 0..16383
        const int n = idx >> 7, k = idx & 127;
        proj_wT[idx] = (bf16_t)proj_w[k * 128 + n];
    } else {
        if (tid < 384) {
            float v = qkv_b[tid];
            if (tid < 128) v *= QKV_SCALE;
            qkv_bs[tid] = v;
        }
    }
}

// ---------------------------------------------------------------- main ----
// One window per 8-wave (512-thread) block; 2 blocks/CU. Wave (a,b2):
// a = head / col-quad, b2 = token HALF (2 token-tiles per wave).
// LDS 64 KiB (identical layout to R9, enum-verified):
//   [0,16384)     xb [64 tok][128 dim] bf16 (swz)  -> os overlay after PV
//   [16384,32768) Qb [64 tok][128 dim] bf16 (swz)
//   [32768,49152) Kb [64 tok][128 dim] bf16 (swz)
//   [49152,65536) Vt [128 dim][64 tok] bf16 (swz), tokens quad-permuted
//                 (slot = 32*b2 + 8*q4 + 4*nt + r) matching Pf packing.
// swizzle byte ^= ((row&7)<<4) on write AND read; rows ≡ c16 (mod 16).
__global__ __launch_bounds__(512, 4) void swin_main_kernel(
    const float* __restrict__ x,
    const bf16_t* __restrict__ qkv_wT,
    const bf16_t* __restrict__ proj_wT,
    const float* __restrict__ qkv_bs,
    const float* __restrict__ proj_b,
    const float* __restrict__ mask_pad,
    const float* __restrict__ bias_t,
    float* __restrict__ out)
{
    __shared__ __align__(16) unsigned char smem[65536];
    const int QB = 16384, KBo = 32768, VT = 49152;

    const int win  = blockIdx.x;
    const int tid  = threadIdx.x;
    const int wv   = tid >> 6;          // 0..7
    const int a    = wv >> 1;           // head / col-quad
    const int b2   = wv & 1;            // token half
    const int lane = tid & 63;
    const int c16  = lane & 15;
    const int q4   = lane >> 4;
    const int swz  = (c16 & 7) << 4;
    const f32x4 zf = {0.f, 0.f, 0.f, 0.f};

    // ---- stage x -> xb: 2 chunks (32 B each) per thread ----
    {
        const float* xg = x + (size_t)win * 6272;
#pragma unroll
        for (int cc = 0; cc < 2; ++cc) {
            const int c   = tid + 512 * cc;        // 0..1023
            const int row = c >> 4;
            const int k8  = (c & 15) << 3;
            const int off = ((row << 8) + (k8 << 1)) ^ ((row & 7) << 4);
            bf16x8 v;
            if (row < 49) {
                const float4 a0 = *(const float4*)(xg + row * 128 + k8);
                const float4 a1 = *(const float4*)(xg + row * 128 + k8 + 4);
                v[0] = (bf16_t)a0.x; v[1] = (bf16_t)a0.y;
                v[2] = (bf16_t)a0.z; v[3] = (bf16_t)a0.w;
                v[4] = (bf16_t)a1.x; v[5] = (bf16_t)a1.y;
                v[6] = (bf16_t)a1.z; v[7] = (bf16_t)a1.w;
            } else {
#pragma unroll
                for (int j = 0; j < 8; ++j) v[j] = (bf16_t)0.0f;
            }
            *(bf16x8*)&smem[off] = v;
        }
    }
    __syncthreads();

    // token rows owned on the col-side (2 tiles)
    int trow[2];
    trow[0] = (16 * (2 * b2 + 0) + c16) << 8;
    trow[1] = (16 * (2 * b2 + 1) + c16) << 8;

    // ================= GEMM1 QK (transposed): outcol tiles 4a..4a+3 =======
    f32x4 qk[4][2];
#pragma unroll
    for (int m = 0; m < 4; ++m) { qk[m][0] = zf; qk[m][1] = zf; }
#pragma unroll
    for (int ks = 0; ks < 4; ++ks) {
        bf16x8 xf[2];
#pragma unroll
        for (int nt = 0; nt < 2; ++nt)
            xf[nt] = *(const bf16x8*)&smem[(trow[nt] + 64 * ks + 16 * q4) ^ swz];
#pragma unroll
        for (int m = 0; m < 4; ++m) {
            const int t = 4 * a + m;         // Q tiles 0-7, K tiles 8-15
            const bf16x8 wf = *(const bf16x8*)(qkv_wT + (16 * t + c16) * 128 + ks * 32 + q4 * 8);
#pragma unroll
            for (int nt = 0; nt < 2; ++nt)
                qk[m][nt] = __builtin_amdgcn_mfma_f32_16x16x32_bf16(wf, xf[nt], qk[m][nt], 0, 0, 0);
        }
    }
    // epilogue: D(row=outcol 16t+4q4+r, col=token) -> Qb/Kb b64 packed
#pragma unroll
    for (int m = 0; m < 4; ++m) {
        const int t = 4 * a + m;
        const float4 bi = *(const float4*)(qkv_bs + 16 * t + 4 * q4);
        const int base = (t < 8) ? QB : KBo;
        const int dimb = (t < 8) ? (32 * t + 8 * q4) : (32 * (t - 8) + 8 * q4);
#pragma unroll
        for (int nt = 0; nt < 2; ++nt) {
            bf16x4 pk;
            pk[0] = (bf16_t)(qk[m][nt][0] + bi.x); pk[1] = (bf16_t)(qk[m][nt][1] + bi.y);
            pk[2] = (bf16_t)(qk[m][nt][2] + bi.z); pk[3] = (bf16_t)(qk[m][nt][3] + bi.w);
            *(bf16x4*)&smem[base + ((trow[nt] + dimb) ^ swz)] = pk;
        }
    }

    // ================= GEMM1 V (natural): V col tiles 2a, 2a+1 ============
    f32x4 va[2][2];      // [mv][nt]
#pragma unroll
    for (int mv = 0; mv < 2; ++mv) { va[mv][0] = zf; va[mv][1] = zf; }
#pragma unroll
    for (int ks = 0; ks < 4; ++ks) {
        bf16x8 xf[2];
#pragma unroll
        for (int nt = 0; nt < 2; ++nt)
            xf[nt] = *(const bf16x8*)&smem[(trow[nt] + 64 * ks + 16 * q4) ^ swz];
#pragma unroll
        for (int mv = 0; mv < 2; ++mv) {
            const int vc = 16 * (2 * a + mv) + c16;   // V outcol 0..127
            const bf16x8 vf = *(const bf16x8*)(qkv_wT + (256 + vc) * 128 + ks * 32 + q4 * 8);
#pragma unroll
            for (int nt = 0; nt < 2; ++nt)
                va[mv][nt] = __builtin_amdgcn_mfma_f32_16x16x32_bf16(xf[nt], vf, va[mv][nt], 0, 0, 0);
        }
    }
    // epilogue: D(row=token 16*(2b2+nt)+4q4+r, col=vcol) -> Vt quad-permuted
#pragma unroll
    for (int mv = 0; mv < 2; ++mv) {
        const int vc = 16 * (2 * a + mv) + c16;
        const float qv = qkv_bs[256 + vc];
#pragma unroll
        for (int nt = 0; nt < 2; ++nt) {
            const int slot2 = (32 * b2 + 8 * q4 + 4 * nt) << 1;
            bf16x4 pk;
            pk[0] = (bf16_t)(va[mv][nt][0] + qv); pk[1] = (bf16_t)(va[mv][nt][1] + qv);
            pk[2] = (bf16_t)(va[mv][nt][2] + qv); pk[3] = (bf16_t)(va[mv][nt][3] + qv);
            *(bf16x4*)&smem[VT + (((vc << 7) + slot2) ^ swz)] = pk;
        }
    }
    __syncthreads();

    // ================= S^T = K · Q^T : 64 kk x 32 q (head a, half b2) =====
    bf16x8 Qf[2];
#pragma unroll
    for (int nt = 0; nt < 2; ++nt)
        Qf[nt] = *(const bf16x8*)&smem[QB + ((trow[nt] + 64 * a + 16 * q4) ^ swz)];
    f32x4 st[4][2];
#pragma unroll
    for (int mtk = 0; mtk < 4; ++mtk) {
        const bf16x8 Kf = *(const bf16x8*)&smem[KBo + ((((16 * mtk + c16) << 8) + 64 * a + 16 * q4) ^ swz)];
        st[mtk][0] = __builtin_amdgcn_mfma_f32_16x16x32_bf16(Kf, Qf[0], zf, 0, 0, 0);
        st[mtk][1] = __builtin_amdgcn_mfma_f32_16x16x32_bf16(Kf, Qf[1], zf, 0, 0, 0);
    }

    // ========== softmax (lane col = q; kk = 16mtk+4q4+r), per q-tile ======
    const float* mp = mask_pad + ((size_t)(win & 63) << 12);
    const float* bt = bias_t + (a << 12);
    bf16x8 Pf[2][2];     // [ntq][ksv]
#pragma unroll
    for (int ntq = 0; ntq < 2; ++ntq) {
        const int qtok = 16 * (2 * b2 + ntq) + c16;
        float mx = -3.0e38f;
#pragma unroll
        for (int mtk = 0; mtk < 4; ++mtk) {
            const float4 mv4 = *(const float4*)(mp + qtok * 64 + 16 * mtk + 4 * q4);
            const float4 bv4 = *(const float4*)(bt + qtok * 64 + 16 * mtk + 4 * q4);
            st[mtk][ntq][0] += mv4.x + bv4.x; st[mtk][ntq][1] += mv4.y + bv4.y;
            st[mtk][ntq][2] += mv4.z + bv4.z; st[mtk][ntq][3] += mv4.w + bv4.w;
#pragma unroll
            for (int r = 0; r < 4; ++r) mx = fmaxf(mx, st[mtk][ntq][r]);
        }
        mx = fmaxf(mx, __shfl_xor(mx, 16));
        mx = fmaxf(mx, __shfl_xor(mx, 32));
        float sm = 0.0f;
#pragma unroll
        for (int mtk = 0; mtk < 4; ++mtk)
#pragma unroll
            for (int r = 0; r < 4; ++r) {
                const float p = __expf(st[mtk][ntq][r] - mx);
                st[mtk][ntq][r] = p;
                sm += p;
            }
        sm += __shfl_xor(sm, 16);
        sm += __shfl_xor(sm, 32);
        const float rp = 1.0f / sm;
#pragma unroll
        for (int ksv = 0; ksv < 2; ++ksv)
#pragma unroll
            for (int r = 0; r < 4; ++r) {
                Pf[ntq][ksv][r]     = (bf16_t)(st[2 * ksv][ntq][r] * rp);
                Pf[ntq][ksv][4 + r] = (bf16_t)(st[2 * ksv + 1][ntq][r] * rp);
            }
    }

    // ================= O^T = V · P^T (A from Vt, natural-enum read) =======
    f32x4 ot[2][2];      // [mtd][ntq]
#pragma unroll
    for (int mtd = 0; mtd < 2; ++mtd) { ot[mtd][0] = zf; ot[mtd][1] = zf; }
#pragma unroll
    for (int ksv = 0; ksv < 2; ++ksv)
#pragma unroll
        for (int mtd = 0; mtd < 2; ++mtd) {
            const bf16x8 av = *(const bf16x8*)&smem[VT + ((((32 * a + 16 * mtd + c16) << 7) + 64 * ksv + 16 * q4) ^ swz)];
#pragma unroll
            for (int ntq = 0; ntq < 2; ++ntq)
                ot[mtd][ntq] = __builtin_amdgcn_mfma_f32_16x16x32_bf16(av, Pf[ntq][ksv], ot[mtd][ntq], 0, 0, 0);
        }

    // ---- O^T -> os (overlay xb; all xb reads finished pre-barrier-2) ----
#pragma unroll
    for (int mtd = 0; mtd < 2; ++mtd)
#pragma unroll
        for (int ntq = 0; ntq < 2; ++ntq) {
            bf16x4 pk;
#pragma unroll
            for (int r = 0; r < 4; ++r) pk[r] = (bf16_t)ot[mtd][ntq][r];
            *(bf16x4*)&smem[(trow[ntq] + ((32 * a + 16 * mtd + 4 * q4) << 1)) ^ swz] = pk;
        }
    __syncthreads();

    // ================= proj (interleaved ocols) ===========================
    const int oc_il = 32 * a + 8 * (c16 >> 2) + (c16 & 3);
    f32x4 pj[2][2];      // [mt][ntq]
#pragma unroll
    for (int mt = 0; mt < 2; ++mt) { pj[mt][0] = zf; pj[mt][1] = zf; }
#pragma unroll
    for (int ks = 0; ks < 4; ++ks) {
        const bf16x8 aw0 = *(const bf16x8*)(proj_wT + (oc_il + 0) * 128 + ks * 32 + q4 * 8);
        const bf16x8 aw1 = *(const bf16x8*)(proj_wT + (oc_il + 4) * 128 + ks * 32 + q4 * 8);
#pragma unroll
        for (int ntq = 0; ntq < 2; ++ntq) {
            const bf16x8 bo = *(const bf16x8*)&smem[(trow[ntq] + 64 * ks + 16 * q4) ^ swz];
            pj[0][ntq] = __builtin_amdgcn_mfma_f32_16x16x32_bf16(aw0, bo, pj[0][ntq], 0, 0, 0);
            pj[1][ntq] = __builtin_amdgcn_mfma_f32_16x16x32_bf16(aw1, bo, pj[1][ntq], 0, 0, 0);
        }
    }

    // ---- store: lane writes 32 contiguous bytes (2x float4) per q-tile ----
    {
        float* og = out + (size_t)win * 6272;
        const int oc0 = 32 * a + 8 * q4;
        const float4 pb0 = *(const float4*)(proj_b + oc0);
        const float4 pb1 = *(const float4*)(proj_b + oc0 + 4);
#pragma unroll
        for (int ntq = 0; ntq < 2; ++ntq) {
            const int tok = 16 * (2 * b2 + ntq) + c16;
            if (tok < 49) {
                float4 v0, v1;
                v0.x = pj[0][ntq][0] + pb0.x; v0.y = pj[0][ntq][1] + pb0.y;
                v0.z = pj[0][ntq][2] + pb0.z; v0.w = pj[0][ntq][3] + pb0.w;
                v1.x = pj[1][ntq][0] + pb1.x; v1.y = pj[1][ntq][1] + pb1.y;
                v1.z = pj[1][ntq][2] + pb1.z; v1.w = pj[1][ntq][3] + pb1.w;
                *(float4*)(og + tok * 128 + oc0)     = v0;
                *(float4*)(og + tok * 128 + oc0 + 4) = v1;
            }
        }
    }
}

// -------------------------------------------------------------- launch ----
extern "C" void kernel_launch(void* const* d_in, const int* in_sizes, int n_in,
                              void* d_out, int out_size, void* d_ws, size_t ws_size,
                              hipStream_t stream) {
    const float* x      = (const float*)d_in[0];
    const float* mask   = (const float*)d_in[1];
    const float* qkv_w  = (const float*)d_in[2];
    const float* qkv_b  = (const float*)d_in[3];
    const float* mlp_w1 = (const float*)d_in[4];
    const float* mlp_b1 = (const float*)d_in[5];
    const float* mlp_w2 = (const float*)d_in[6];
    const float* mlp_b2 = (const float*)d_in[7];
    const float* proj_w = (const float*)d_in[8];
    const float* proj_b = (const float*)d_in[9];
    float* out = (float*)d_out;

    unsigned char* ws = (unsigned char*)d_ws;
    bf16_t* qkv_wT   = (bf16_t*)(ws + WS_QKVWT);
    bf16_t* proj_wT  = (bf16_t*)(ws + WS_PROJWT);
    float*  qkv_bs   = (float*)(ws + WS_QKVB);
    float*  mask_pad = (float*)(ws + WS_MASKP);
    float*  bias_t   = (float*)(ws + WS_BIAST);

    hipLaunchKernelGGL(prep_kernel, dim3(1297), dim3(256), 0, stream,
                       mask, qkv_w, qkv_b, mlp_w1, mlp_b1, mlp_w2, mlp_b2, proj_w,
                       qkv_wT, proj_wT, qkv_bs, mask_pad, bias_t);
    hipLaunchKernelGGL(swin_main_kernel, dim3(16384), dim3(512), 0, stream,
                       x, qkv_wT, proj_wT, qkv_bs, proj_b, mask_pad, bias_t, out);
}